// Round 4
// baseline (174.649 us; speedup 1.0000x reference)
//
#include <hip/hip_runtime.h>
#include <hip/hip_cooperative_groups.h>

namespace cg = cooperative_groups;

// CHMM forward-backward, clone-structured deterministic emission.
// Single cooperative kernel: 256 blocks x 256 threads, 4 grid syncs.
// Chunk matrices live in LDS from gather to rescan. Output written once.

#define NSTATES 4096
#define NBLK    8
#define LSEQ    8192
#define NSTEPS  8191
#define CHK     32
#define NCH     256
#define NGRP    16
#define GSZ     16

// ws float offsets
#define OFF_P   0u       // [NCH*64]  chunk products, col-major [c*64 + j*8 + i]
#define OFF_G2  16384u   // [NGRP*64] group products, col-major
#define OFF_AG  17408u   // [NGRP*8]  alpha at group starts (normalized)
#define OFF_BG  17536u   // [NGRP*8]  beta  at group ends   (normalized)
#define OFF_LL0 17664u   // log(c0)
#define OFF_LLP 17672u   // [NCH] per-chunk log-lik partials
#define OFF_G   17928u   // [LSEQ*8] compact normalized gamma

__device__ __forceinline__ float exp_renorm(float x, float ref) {
    int k = (int)((__float_as_uint(ref) >> 23) & 0xff) - 127;
    return ldexpf(x, -k);
}

__global__ __launch_bounds__(256) void kFB(const float* __restrict__ T,
                                           const float* __restrict__ Pi,
                                           const int* __restrict__ obs,
                                           float* __restrict__ out,
                                           float* __restrict__ ws)
{
    cg::grid_group grid = cg::this_grid();
    __shared__ float sM[CHK * 64];        // this block's chunk, col-major/step
    __shared__ float sA[(CHK + 1) * 8];   // alpha history
    __shared__ float sB[(CHK + 1) * 8];   // beta history
    __shared__ float sGv[33 * 8];         // staged G rows for the stream phase
    __shared__ int   sWs[33];             // staged window starts (8*obs[t])
    const int tid = threadIdx.x;
    const int b = blockIdx.x;
    const int t0 = b * CHK;
    const int n = min(CHK, NSTEPS - t0);  // 32; last block 31

    // ---- Phase 1: gather chunk matrices into LDS + chunk product ----------
    {
        int dt = tid >> 3, i = tid & 7;
        if (dt < n) {
            int t = t0 + dt;
            int row = obs[t] * NBLK + i;
            int col = obs[t + 1] * NBLK;
            const float4* src = reinterpret_cast<const float4*>(T + (size_t)row * NSTATES + col);
            float4 v0 = src[0], v1 = src[1];
            float vv[8] = {v0.x, v0.y, v0.z, v0.w, v1.x, v1.y, v1.z, v1.w};
            float* base = &sM[dt * 64 + i];   // col-major: [dt*64 + j*8 + i]
#pragma unroll
            for (int j = 0; j < 8; ++j) base[j * 8] = vv[j];
        }
    }
    __syncthreads();
    if (tid < 64) {
        const int i = tid >> 3, j = tid & 7;
        float p = sM[j * 8 + i];
        float m[8], mn[8];
#pragma unroll
        for (int k = 0; k < 8; ++k) m[k] = sM[64 + j * 8 + k];
        for (int dt = 1; dt < n; ++dt) {
            int dtn = min(dt + 1, n - 1);
#pragma unroll
            for (int k = 0; k < 8; ++k) mn[k] = sM[dtn * 64 + j * 8 + k];
            float pn = 0.f;
#pragma unroll
            for (int k = 0; k < 8; ++k) pn = fmaf(__shfl(p, i * 8 + k, 64), m[k], pn);
            if ((dt & 3) == 0) pn = exp_renorm(pn, __shfl(pn, 0, 64));
            p = pn;
#pragma unroll
            for (int k = 0; k < 8; ++k) m[k] = mn[k];
        }
        p = exp_renorm(p, __shfl(p, 0, 64));
        ws[OFF_P + b * 64 + j * 8 + i] = p;   // col-major
    }
    grid.sync();

    // ---- Phase 2a: 16 group products (blocks 0..15, wave 0) ---------------
    if (b < NGRP && tid < 64) {
        const int i = tid >> 3, j = tid & 7;
        const float* Pg = ws + OFF_P;
        float p = Pg[(GSZ * b) * 64 + j * 8 + i];
        float4 c0 = *reinterpret_cast<const float4*>(&Pg[(GSZ * b + 1) * 64 + j * 8]);
        float4 c1 = *reinterpret_cast<const float4*>(&Pg[(GSZ * b + 1) * 64 + j * 8 + 4]);
        for (int r = 1; r < GSZ; ++r) {
            int rn = min(r + 1, GSZ - 1);
            float4 n0 = *reinterpret_cast<const float4*>(&Pg[(GSZ * b + rn) * 64 + j * 8]);
            float4 n1 = *reinterpret_cast<const float4*>(&Pg[(GSZ * b + rn) * 64 + j * 8 + 4]);
            float m[8] = {c0.x, c0.y, c0.z, c0.w, c1.x, c1.y, c1.z, c1.w};
            float pn = 0.f;
#pragma unroll
            for (int k = 0; k < 8; ++k) pn = fmaf(__shfl(p, i * 8 + k, 64), m[k], pn);
            if ((r & 1) == 0 || r == GSZ - 1) pn = exp_renorm(pn, __shfl(pn, 0, 64));
            p = pn;
            c0 = n0; c1 = n1;
        }
        ws[OFF_G2 + b * 64 + j * 8 + i] = p;
    }
    grid.sync();

    // ---- Phase 2b: dual scan over group products (block 0, lanes 0-15) ----
    if (b == 0 && tid < 16) {
        const int grp = tid >> 3, l8 = tid & 7;
        float v[8];
        int o0 = obs[0];
        float a = Pi[o0 * NBLK + l8];
        float s0 = a;
        s0 += __shfl_xor(s0, 1); s0 += __shfl_xor(s0, 2); s0 += __shfl_xor(s0, 4);
        float rs0 = 1.0f / s0;
#pragma unroll
        for (int q = 0; q < 8; ++q) v[q] = grp ? 0.125f : __shfl(a, q, 8) * rs0;
        if (tid == 0) ws[OFF_LL0] = __logf(s0);
        ws[grp ? (OFF_BG + (NGRP - 1) * 8 + l8) : (OFF_AG + l8)] = v[l8];
        int st = grp ? 8 : 1;
        int boff = grp ? l8 : l8 * 8;
        for (int r = 0; r < NGRP - 1; ++r) {
            int gi = grp ? (NGRP - 1 - r) : r;
            const float* mb = ws + OFF_G2 + gi * 64 + boff;
            float m[8];
#pragma unroll
            for (int q = 0; q < 8; ++q) m[q] = mb[q * st];
            float u = 0.f;
#pragma unroll
            for (int q = 0; q < 8; ++q) u = fmaf(v[q], m[q], u);
            float s = 0.f;
#pragma unroll
            for (int q = 0; q < 8; ++q) { float x = __shfl(u, q, 8); v[q] = x; s += x; }
            float rs = 1.0f / s;
#pragma unroll
            for (int q = 0; q < 8; ++q) v[q] *= rs;
            ws[grp ? (OFF_BG + (NGRP - 2 - r) * 8 + l8)
                   : (OFF_AG + (r + 1) * 8 + l8)] = v[l8];
        }
    }
    grid.sync();

    // ---- Phase 3a: boundary advance + within-chunk dual scan + compact G --
    if (tid < 16) {
        const int grp = tid >> 3, l8 = tid & 7;
        const int g = b >> 4, r = b & 15;
        float v[8];
#pragma unroll
        for (int q = 0; q < 8; ++q)
            v[q] = grp ? ws[OFF_BG + g * 8 + q] : ws[OFF_AG + g * 8 + q];
        int st = grp ? 8 : 1;
        int boff = grp ? l8 : l8 * 8;
        const int cnt = grp ? (GSZ - 1 - r) : r;   // predicated trip count
        for (int q = 0; q < GSZ - 1; ++q) {
            bool act = q < cnt;
            int qc = act ? q : 0;
            int cidx = grp ? (GSZ * g + GSZ - 1 - qc) : (GSZ * g + qc);
            const float* mb = ws + OFF_P + cidx * 64 + boff;
            float m[8];
#pragma unroll
            for (int k = 0; k < 8; ++k) m[k] = mb[k * st];
            float u = 0.f;
#pragma unroll
            for (int k = 0; k < 8; ++k) u = fmaf(v[k], m[k], u);
            float s = 0.f;
            float vn[8];
#pragma unroll
            for (int k = 0; k < 8; ++k) { float x = __shfl(u, k, 8); vn[k] = x; s += x; }
            float rs = 1.0f / s;
#pragma unroll
            for (int k = 0; k < 8; ++k) v[k] = act ? vn[k] * rs : v[k];
        }
        // v = AB[b] (fwd half) / BB[b] (bwd half); within-chunk dual scan
        float* hist = grp ? sB : sA;
        hist[(grp ? n : 0) * 8 + l8] = v[l8];
        int mt0 = grp ? (n - 1) : 0;
        float m[8], mn[8];
#pragma unroll
        for (int q = 0; q < 8; ++q) m[q] = sM[mt0 * 64 + boff + q * st];
        float ll = 0.f;
        for (int rr = 0; rr < n; ++rr) {
            int rn2 = min(rr + 1, n - 1);
            int mtn = grp ? (n - 1 - rn2) : rn2;
#pragma unroll
            for (int q = 0; q < 8; ++q) mn[q] = sM[mtn * 64 + boff + q * st];
            float u = 0.f;
#pragma unroll
            for (int q = 0; q < 8; ++q) u = fmaf(v[q], m[q], u);
            float s = 0.f;
#pragma unroll
            for (int q = 0; q < 8; ++q) { float x = __shfl(u, q, 8); v[q] = x; s += x; }
            float rs = 1.0f / s;
#pragma unroll
            for (int q = 0; q < 8; ++q) v[q] *= rs;
            hist[(grp ? (n - 1 - rr) : (rr + 1)) * 8 + l8] = v[l8];
            ll += __logf(s);
#pragma unroll
            for (int q = 0; q < 8; ++q) m[q] = mn[q];
        }
        if (tid == 0) ws[OFF_LLP + b] = ll;
    }
    __syncthreads();
    {   // compact normalized gamma for this block's 32 rows (all 256 threads)
        const int rr = tid >> 3, i = tid & 7;   // t0+rr <= 8191 always
        float gp = sA[rr * 8 + i] * sB[rr * 8 + i];
        float gs = gp;
        gs += __shfl_xor(gs, 1); gs += __shfl_xor(gs, 2); gs += __shfl_xor(gs, 4);
        ws[OFF_G + (size_t)(t0 + rr) * 8 + i] = gp / gs;
    }
    grid.sync();

    // ---- Phase 3b: write-once output stream -------------------------------
    float llsum = 0.f;
    if (b == 0 && tid < 64) {   // deterministic log-lik reduce (fixed tree)
        float part = 0.f;
#pragma unroll
        for (int q = 0; q < 4; ++q) part += ws[OFF_LLP + tid * 4 + q];
        part += __shfl_xor(part, 32); part += __shfl_xor(part, 16);
        part += __shfl_xor(part, 8);  part += __shfl_xor(part, 4);
        part += __shfl_xor(part, 2);  part += __shfl_xor(part, 1);
        llsum = part + ws[OFF_LL0];
    }
    // stage window starts + G rows for rows [32b-1, 32b+31] into LDS
    for (int li = tid; li < 33; li += 256) {
        int t = t0 - 1 + li;
        sWs[li] = (t >= 0 && t < LSEQ) ? obs[t] * NBLK : 0;
    }
    for (int e = tid; e < 33 * 8; e += 256) {
        int li = e >> 3, i = e & 7;
        int t = t0 - 1 + li;
        sGv[e] = (t >= 0 && t < LSEQ) ? ws[OFF_G + (size_t)t * 8 + i] : 0.f;
    }
    __syncthreads();
    {
        float4* o4 = reinterpret_cast<float4*>(out);
        const int kbase = b * 32768;
#pragma unroll 4
        for (int it = 0; it < 128; ++it) {
            int k = kbase + it * 256 + tid;
            float v[4];
#pragma unroll
            for (int e = 0; e < 4; ++e) {
                int gg = 4 * k + e - 1;       // gamma flat index; -1 only at k=0
                gg = gg < 0 ? 0 : gg;
                int t = gg >> 12;
                int col = gg & (NSTATES - 1);
                int li = t - t0 + 1;          // in [0,32]
                int d = col - sWs[li];
                v[e] = ((unsigned)d < 8u) ? sGv[li * 8 + d] : 0.f;
            }
            o4[k] = make_float4(v[0], v[1], v[2], v[3]);
        }
    }
    if (b == 0 && tid == 0) out[0] = llsum;   // same thread wrote o4[0]: ordered
    if (b == NCH - 1 && tid == 255) {         // final extra float: t=8191,col=4095
        int d = (NSTATES - 1) - sWs[32];
        out[(size_t)LSEQ * NSTATES] = ((unsigned)d < 8u) ? sGv[32 * 8 + d] : 0.f;
    }
}

extern "C" void kernel_launch(void* const* d_in, const int* in_sizes, int n_in,
                              void* d_out, int out_size, void* d_ws, size_t ws_size,
                              hipStream_t stream)
{
    const float* T   = (const float*)d_in[0];
    const float* Pi  = (const float*)d_in[1];
    const int*   obs = (const int*)d_in[2];
    float* out = (float*)d_out;
    float* ws  = (float*)d_ws;

    void* args[] = {(void*)&T, (void*)&Pi, (void*)&obs, (void*)&out, (void*)&ws};
    hipLaunchCooperativeKernel((const void*)kFB, dim3(NCH), dim3(256), args, 0, stream);
}

// Round 5
// 80.184 us; speedup vs baseline: 2.1781x; 2.1781x over previous
//
#include <hip/hip_runtime.h>

// CHMM forward-backward, clone-structured deterministic emission (n_clones=8).
// Single cooperative kernel, NO grid.sync: point-to-point release/acquire flag
// dataflow (AGENT scope). Waves 1-3 of each block zero-fill that block's 32
// output rows (BW-bound, hides the whole scan chain); wave 0 runs the chunked
// scan; one __syncthreads joins, then the block scatters its gamma windows
// into its own rows. Replays are value-idempotent -> stale flags are safe.

#define NSTATES 4096
#define NBLK    8
#define LSEQ    8192
#define NSTEPS  8191
#define CHK     32
#define NCH     256
#define NGRP    16
#define GSZ     16

// ws float offsets
#define OFF_P   0u       // [NCH*64]  chunk products, col-major [c*64 + col*8 + row]
#define OFF_G2  16384u   // [NGRP*64] group products, col-major
#define OFF_LLP 17408u   // [NCH]     per-chunk log-lik partials
// ws uint offsets (flags)
#define FLG_F1  17664u   // [NCH]
#define FLG_F2  17920u   // [NGRP]
#define FLG_F3  17936u   // [NCH]
#define MAGIC   0x5A17C0DEu

__device__ __forceinline__ float exp_renorm(float x, float ref) {
    int k = (int)((__float_as_uint(ref) >> 23) & 0xff) - 127;
    return ldexpf(x, -k);
}

__global__ __launch_bounds__(256) void kFB(const float* __restrict__ T,
                                           const float* __restrict__ Pi,
                                           const int* __restrict__ obs,
                                           float* __restrict__ out,
                                           float* __restrict__ ws)
{
    __shared__ float sM[CHK * 64];        // own chunk matrices, col-major/step
    __shared__ float sG2[NGRP * 64];      // staged group products
    __shared__ float sGP[GSZ * 64];       // staged own-group chunk products
    __shared__ float sA[(CHK + 1) * 8];   // alpha history
    __shared__ float sB[(CHK + 1) * 8];   // beta history
    __shared__ int   sObs[CHK];
    unsigned* flg = reinterpret_cast<unsigned*>(ws);
    const int tid = threadIdx.x;
    const int b = blockIdx.x;
    const int g = b >> 4, rIn = b & 15;
    const int t0 = b * CHK;
    const int n = min(CHK, NSTEPS - t0);  // 32; block 255: 31
    float ll0 = 0.f;

    // ---- gather own chunk's 8x8 T-blocks into LDS (all 256 threads) -------
    {
        int dt = tid >> 3, i = tid & 7;
        if (dt < n) {
            int t = t0 + dt;
            int row = obs[t] * NBLK + i;
            int col = obs[t + 1] * NBLK;
            const float4* src = reinterpret_cast<const float4*>(T + (size_t)row * NSTATES + col);
            float4 v0 = src[0], v1 = src[1];
            float vv[8] = {v0.x, v0.y, v0.z, v0.w, v1.x, v1.y, v1.z, v1.w};
            float* base = &sM[dt * 64 + i];            // [dt*64 + col*8 + row]
#pragma unroll
            for (int j = 0; j < 8; ++j) base[j * 8] = vv[j];
        }
        if (tid < CHK) sObs[tid] = obs[t0 + tid];
    }
    __syncthreads();

    if (tid >= 64) {
        // ---- fill waves (1-3): zero own rows [32b, 32b+32) of gamma -------
        float* p = out + (size_t)131072 * b + 1;       // row-aligned in gamma
        int wt = tid - 64;
        if (wt < 3) p[wt] = 0.f;                       // unaligned head
        float4* b4 = reinterpret_cast<float4*>(p + 3);
        const float4 z = make_float4(0.f, 0.f, 0.f, 0.f);
#pragma unroll 4
        for (int idx = wt; idx < 32767; idx += 192) b4[idx] = z;
        if (wt == 0) p[131071] = 0.f;                  // tail float
    } else {
        // ================= wave 0: the scan chain ==========================
        const int i = tid >> 3, j = tid & 7;
        // ---- chunk product: lane (i,j) holds P[i][j] ----
        {
            float p = sM[j * 8 + i];
            float m[8], mn[8];
#pragma unroll
            for (int k = 0; k < 8; ++k) m[k] = sM[64 + j * 8 + k];
            for (int dt = 1; dt < n; ++dt) {
                int dtn = min(dt + 1, n - 1);
#pragma unroll
                for (int k = 0; k < 8; ++k) mn[k] = sM[dtn * 64 + j * 8 + k];
                float pn = 0.f;
#pragma unroll
                for (int k = 0; k < 8; ++k) pn = fmaf(__shfl(p, i * 8 + k, 64), m[k], pn);
                if ((dt & 3) == 0) pn = exp_renorm(pn, __shfl(pn, 0, 64));
                p = pn;
#pragma unroll
                for (int k = 0; k < 8; ++k) m[k] = mn[k];
            }
            p = exp_renorm(p, __shfl(p, 0, 64));
            ws[OFF_P + b * 64 + j * 8 + i] = p;
        }
        if (tid == 0)
            __hip_atomic_store(&flg[FLG_F1 + b], MAGIC, __ATOMIC_RELEASE, __HIP_MEMORY_SCOPE_AGENT);

        // ---- group duty (blocks 0..15): product of group's 16 P's ----
        if (b < NGRP) {
            for (;;) {
                bool ok = true;
                if (tid < GSZ)
                    ok = __hip_atomic_load(&flg[FLG_F1 + GSZ * b + tid], __ATOMIC_ACQUIRE, __HIP_MEMORY_SCOPE_AGENT) == MAGIC;
                if (__all(ok)) break;
                __builtin_amdgcn_s_sleep(1);
            }
            const float* Pg = ws + OFF_P;
            float p = Pg[(GSZ * b) * 64 + j * 8 + i];
            float4 c0 = *reinterpret_cast<const float4*>(&Pg[(GSZ * b + 1) * 64 + j * 8]);
            float4 c1 = *reinterpret_cast<const float4*>(&Pg[(GSZ * b + 1) * 64 + j * 8 + 4]);
            for (int r = 1; r < GSZ; ++r) {
                int rn = min(r + 1, GSZ - 1);
                float4 n0 = *reinterpret_cast<const float4*>(&Pg[(GSZ * b + rn) * 64 + j * 8]);
                float4 n1 = *reinterpret_cast<const float4*>(&Pg[(GSZ * b + rn) * 64 + j * 8 + 4]);
                float m[8] = {c0.x, c0.y, c0.z, c0.w, c1.x, c1.y, c1.z, c1.w};
                float pn = 0.f;
#pragma unroll
                for (int k = 0; k < 8; ++k) pn = fmaf(__shfl(p, i * 8 + k, 64), m[k], pn);
                if ((r & 1) == 0 || r == GSZ - 1) pn = exp_renorm(pn, __shfl(pn, 0, 64));
                p = pn;
                c0 = n0; c1 = n1;
            }
            ws[OFF_G2 + b * 64 + j * 8 + i] = p;
            if (tid == 0)
                __hip_atomic_store(&flg[FLG_F2 + b], MAGIC, __ATOMIC_RELEASE, __HIP_MEMORY_SCOPE_AGENT);
        }

        // ---- acquire all 16 F2 + own group's 16 F1 ----
        for (;;) {
            bool ok = true;
            if (tid < NGRP)
                ok = __hip_atomic_load(&flg[FLG_F2 + tid], __ATOMIC_ACQUIRE, __HIP_MEMORY_SCOPE_AGENT) == MAGIC;
            else if (tid < NGRP + GSZ)
                ok = __hip_atomic_load(&flg[FLG_F1 + GSZ * g + (tid - NGRP)], __ATOMIC_ACQUIRE, __HIP_MEMORY_SCOPE_AGENT) == MAGIC;
            if (__all(ok)) break;
            __builtin_amdgcn_s_sleep(1);
        }
        // ---- stage G2 (all 16) + own group's P into LDS (one burst) ----
        {
            const float4* s1 = reinterpret_cast<const float4*>(ws + OFF_G2);
            float4* d1 = reinterpret_cast<float4*>(sG2);
            for (int q = tid; q < NGRP * 16; q += 64) d1[q] = s1[q];
            const float4* s2 = reinterpret_cast<const float4*>(ws + OFF_P + (size_t)g * GSZ * 64);
            float4* d2 = reinterpret_cast<float4*>(sGP);
            for (int q = tid; q < GSZ * 16; q += 64) d2[q] = s2[q];
        }

        if (tid < 16) {
            const int grp = tid >> 3, l8 = tid & 7;
            const int st = grp ? 8 : 1;
            const int boff = grp ? l8 : l8 * 8;
            // ---- redundant global dual scan over 16 group products ----
            float v[8], vb[8];
            {
                float a = Pi[obs[0] * NBLK + l8];
                float s0 = a;
                s0 += __shfl_xor(s0, 1); s0 += __shfl_xor(s0, 2); s0 += __shfl_xor(s0, 4);
                float rs0 = 1.0f / s0;
#pragma unroll
                for (int q = 0; q < 8; ++q) v[q] = grp ? 0.125f : __shfl(a, q, 8) * rs0;
                ll0 = __logf(s0);
            }
            const int cap = grp ? (NGRP - 1 - g) : g;
            if (cap == 0) {
#pragma unroll
                for (int q = 0; q < 8; ++q) vb[q] = v[q];
            }
            for (int r = 0; r < NGRP - 1; ++r) {
                int gi = grp ? (NGRP - 1 - r) : r;
                const float* mb = &sG2[gi * 64 + boff];
                float m[8];
#pragma unroll
                for (int q = 0; q < 8; ++q) m[q] = mb[q * st];
                float u = 0.f;
#pragma unroll
                for (int q = 0; q < 8; ++q) u = fmaf(v[q], m[q], u);
                float s = 0.f;
#pragma unroll
                for (int q = 0; q < 8; ++q) { float x = __shfl(u, q, 8); v[q] = x; s += x; }
                float rs = 1.0f / s;
#pragma unroll
                for (int q = 0; q < 8; ++q) v[q] *= rs;
                if (r + 1 == cap) {
#pragma unroll
                    for (int q = 0; q < 8; ++q) vb[q] = v[q];
                }
            }
            // ---- predicated advance to own chunk boundary (<=15 steps) ----
#pragma unroll
            for (int q = 0; q < 8; ++q) v[q] = vb[q];
            const int cnt = grp ? (GSZ - 1 - rIn) : rIn;
            for (int q = 0; q < GSZ - 1; ++q) {
                bool act = q < cnt;
                int qc = act ? q : 0;
                int lc = grp ? (GSZ - 1 - qc) : qc;
                const float* mb = &sGP[lc * 64 + boff];
                float m[8];
#pragma unroll
                for (int k = 0; k < 8; ++k) m[k] = mb[k * st];
                float u = 0.f;
#pragma unroll
                for (int k = 0; k < 8; ++k) u = fmaf(v[k], m[k], u);
                float s = 0.f;
                float vn[8];
#pragma unroll
                for (int k = 0; k < 8; ++k) { float x = __shfl(u, k, 8); vn[k] = x; s += x; }
                float rs = 1.0f / s;
#pragma unroll
                for (int k = 0; k < 8; ++k) v[k] = act ? vn[k] * rs : v[k];
            }
            // ---- within-chunk dual rescan from sM ----
            float* hist = grp ? sB : sA;
            hist[(grp ? n : 0) * 8 + l8] = v[l8];
            int mt0 = grp ? (n - 1) : 0;
            float m[8], mn[8];
#pragma unroll
            for (int q = 0; q < 8; ++q) m[q] = sM[mt0 * 64 + boff + q * st];
            float ll = 0.f;
            for (int rr = 0; rr < n; ++rr) {
                int rn2 = min(rr + 1, n - 1);
                int mtn = grp ? (n - 1 - rn2) : rn2;
#pragma unroll
                for (int q = 0; q < 8; ++q) mn[q] = sM[mtn * 64 + boff + q * st];
                float u = 0.f;
#pragma unroll
                for (int q = 0; q < 8; ++q) u = fmaf(v[q], m[q], u);
                float s = 0.f;
#pragma unroll
                for (int q = 0; q < 8; ++q) { float x = __shfl(u, q, 8); v[q] = x; s += x; }
                float rs = 1.0f / s;
#pragma unroll
                for (int q = 0; q < 8; ++q) v[q] *= rs;
                hist[(grp ? (n - 1 - rr) : (rr + 1)) * 8 + l8] = v[l8];
                ll += __logf(s);
#pragma unroll
                for (int q = 0; q < 8; ++q) m[q] = mn[q];
            }
            if (tid == 0) {
                ws[OFF_LLP + b] = ll;
                __hip_atomic_store(&flg[FLG_F3 + b], MAGIC, __ATOMIC_RELEASE, __HIP_MEMORY_SCOPE_AGENT);
            }
        }
    }
    __syncthreads();   // join fill + scan; own rows are zeroed, sA/sB ready

    // ---- scatter gamma windows into own pre-zeroed rows (256 threads) -----
    {
        const int rr = tid >> 3, ii = tid & 7;
        float gp = sA[rr * 8 + ii] * sB[rr * 8 + ii];
        float gs = gp;
        gs += __shfl_xor(gs, 1); gs += __shfl_xor(gs, 2); gs += __shfl_xor(gs, 4);
        out[1 + (size_t)(t0 + rr) * NSTATES + sObs[rr] * NBLK + ii] = gp / gs;
    }

    // ---- block 0, wave 0: deterministic log-lik reduction -> out[0] -------
    if (b == 0 && tid < 64) {
        for (;;) {
            bool ok = true;
#pragma unroll
            for (int q = 0; q < 4; ++q)
                ok = ok && (__hip_atomic_load(&flg[FLG_F3 + tid * 4 + q], __ATOMIC_ACQUIRE, __HIP_MEMORY_SCOPE_AGENT) == MAGIC);
            if (__all(ok)) break;
            __builtin_amdgcn_s_sleep(1);
        }
        float part = 0.f;
#pragma unroll
        for (int q = 0; q < 4; ++q) part += ws[OFF_LLP + tid * 4 + q];
        part += __shfl_xor(part, 32); part += __shfl_xor(part, 16);
        part += __shfl_xor(part, 8);  part += __shfl_xor(part, 4);
        part += __shfl_xor(part, 2);  part += __shfl_xor(part, 1);
        if (tid == 0) out[0] = part + ll0;
    }
}

extern "C" void kernel_launch(void* const* d_in, const int* in_sizes, int n_in,
                              void* d_out, int out_size, void* d_ws, size_t ws_size,
                              hipStream_t stream)
{
    const float* T   = (const float*)d_in[0];
    const float* Pi  = (const float*)d_in[1];
    const int*   obs = (const int*)d_in[2];
    float* out = (float*)d_out;
    float* ws  = (float*)d_ws;

    void* args[] = {(void*)&T, (void*)&Pi, (void*)&obs, (void*)&out, (void*)&ws};
    hipLaunchCooperativeKernel((const void*)kFB, dim3(NCH), dim3(256), args, 0, stream);
}

// Round 6
// 77.405 us; speedup vs baseline: 2.2563x; 1.0359x over previous
//
#include <hip/hip_runtime.h>

// CHMM forward-backward, clone-structured deterministic emission (n_clones=8).
// Single cooperative kernel, point-to-point flag dataflow with RELAXED
// agent-scope atomics only (no acquire/release -> no bulk L2 inv/wb ops that
// throttled R5's fill). Producer ordering: payload stores (write-through to
// MALL) -> s_waitcnt vmcnt(0) -> flag store. Consumers poll relaxed flags and
// read payloads as relaxed atomics (bypass stale per-XCD L2).
// Waves 1-3 of each block zero-fill that block's 32 output rows (BW-bound,
// hides the whole scan chain); wave 0 runs the chunked scan; one
// __syncthreads joins; block scatters its gamma windows into its own rows.
// Replays are value-idempotent -> stale flags are safe.

#define NSTATES 4096
#define NBLK    8
#define LSEQ    8192
#define NSTEPS  8191
#define CHK     32
#define NCH     256
#define NGRP    16
#define GSZ     16

// ws float offsets
#define OFF_P   0u       // [NCH*64]  chunk products, col-major [c*64 + col*8 + row]
#define OFF_G2  16384u   // [NGRP*64] group products, col-major
#define OFF_LLP 17408u   // [NCH]     per-chunk log-lik partials
// ws uint offsets (flags)
#define FLG_F1  17664u   // [NCH]
#define FLG_F2  17920u   // [NGRP]
#define FLG_F3  17936u   // [NCH]
#define MAGIC   0x5A17C0DEu

__device__ __forceinline__ float aload(float* p) {
    return __hip_atomic_load(p, __ATOMIC_RELAXED, __HIP_MEMORY_SCOPE_AGENT);
}
__device__ __forceinline__ void astore(float* p, float v) {
    __hip_atomic_store(p, v, __ATOMIC_RELAXED, __HIP_MEMORY_SCOPE_AGENT);
}
__device__ __forceinline__ unsigned aloadu(unsigned* p) {
    return __hip_atomic_load(p, __ATOMIC_RELAXED, __HIP_MEMORY_SCOPE_AGENT);
}
__device__ __forceinline__ void astoreu(unsigned* p, unsigned v) {
    __hip_atomic_store(p, v, __ATOMIC_RELAXED, __HIP_MEMORY_SCOPE_AGENT);
}
#define VMFENCE() asm volatile("s_waitcnt vmcnt(0)" ::: "memory")

__device__ __forceinline__ float exp_renorm(float x, float ref) {
    int k = (int)((__float_as_uint(ref) >> 23) & 0xff) - 127;
    return ldexpf(x, -k);
}

__global__ __launch_bounds__(256) void kFB(const float* __restrict__ T,
                                           const float* __restrict__ Pi,
                                           const int* __restrict__ obs,
                                           float* __restrict__ out,
                                           float* __restrict__ ws)
{
    __shared__ float sM[CHK * 64];        // own chunk matrices, col-major/step
    __shared__ float sG2[NGRP * 64];      // staged group products
    __shared__ float sGP[GSZ * 64];       // staged own-group chunk products
    __shared__ float sA[(CHK + 1) * 8];   // alpha history
    __shared__ float sB[(CHK + 1) * 8];   // beta history
    __shared__ int   sObs[CHK];
    unsigned* flg = reinterpret_cast<unsigned*>(ws);
    const int tid = threadIdx.x;
    const int b = blockIdx.x;
    const int g = b >> 4, rIn = b & 15;
    const int t0 = b * CHK;
    const int n = min(CHK, NSTEPS - t0);  // 32; block 255: 31
    float ll0 = 0.f;

    // ---- gather own chunk's 8x8 T-blocks into LDS (all 256 threads) -------
    {
        int dt = tid >> 3, i = tid & 7;
        if (dt < n) {
            int t = t0 + dt;
            int row = obs[t] * NBLK + i;
            int col = obs[t + 1] * NBLK;
            const float4* src = reinterpret_cast<const float4*>(T + (size_t)row * NSTATES + col);
            float4 v0 = src[0], v1 = src[1];
            float vv[8] = {v0.x, v0.y, v0.z, v0.w, v1.x, v1.y, v1.z, v1.w};
            float* base = &sM[dt * 64 + i];            // [dt*64 + col*8 + row]
#pragma unroll
            for (int j = 0; j < 8; ++j) base[j * 8] = vv[j];
        }
        if (tid < CHK) sObs[tid] = obs[t0 + tid];
    }
    __syncthreads();

    if (tid >= 64) {
        // ---- fill waves (1-3): zero own rows [32b, 32b+32) of gamma -------
        float* p = out + (size_t)131072 * b + 1;       // row-aligned in gamma
        int wt = tid - 64;
        if (wt < 3) p[wt] = 0.f;                       // unaligned head
        float4* b4 = reinterpret_cast<float4*>(p + 3);
        const float4 z = make_float4(0.f, 0.f, 0.f, 0.f);
#pragma unroll 4
        for (int idx = wt; idx < 32767; idx += 192) b4[idx] = z;
        if (wt == 0) p[131071] = 0.f;                  // tail float
    } else {
        // ================= wave 0: the scan chain ==========================
        const int i = tid >> 3, j = tid & 7;
        // ---- chunk product: lane (i,j) holds P[i][j] ----
        {
            float p = sM[j * 8 + i];
            float m[8], mn[8];
#pragma unroll
            for (int k = 0; k < 8; ++k) m[k] = sM[64 + j * 8 + k];
            for (int dt = 1; dt < n; ++dt) {
                int dtn = min(dt + 1, n - 1);
#pragma unroll
                for (int k = 0; k < 8; ++k) mn[k] = sM[dtn * 64 + j * 8 + k];
                float pn = 0.f;
#pragma unroll
                for (int k = 0; k < 8; ++k) pn = fmaf(__shfl(p, i * 8 + k, 64), m[k], pn);
                if ((dt & 3) == 0) pn = exp_renorm(pn, __shfl(pn, 0, 64));
                p = pn;
#pragma unroll
                for (int k = 0; k < 8; ++k) m[k] = mn[k];
            }
            p = exp_renorm(p, __shfl(p, 0, 64));
            astore(&ws[OFF_P + b * 64 + j * 8 + i], p);
        }
        VMFENCE();
        if (tid == 0) astoreu(&flg[FLG_F1 + b], MAGIC);

        // ---- group duty (blocks 0..15): product of group's 16 P's ----
        if (b < NGRP) {
            for (;;) {
                bool ok = true;
                if (tid < GSZ)
                    ok = aloadu(&flg[FLG_F1 + GSZ * b + tid]) == MAGIC;
                if (__all(ok)) break;
                __builtin_amdgcn_s_sleep(1);
            }
            float* Pg = ws + OFF_P;
            float p = aload(&Pg[(GSZ * b) * 64 + j * 8 + i]);
            float m[8], mn[8];
#pragma unroll
            for (int k = 0; k < 8; ++k) m[k] = aload(&Pg[(GSZ * b + 1) * 64 + j * 8 + k]);
            for (int r = 1; r < GSZ; ++r) {
                int rn = min(r + 1, GSZ - 1);
#pragma unroll
                for (int k = 0; k < 8; ++k) mn[k] = aload(&Pg[(GSZ * b + rn) * 64 + j * 8 + k]);
                float pn = 0.f;
#pragma unroll
                for (int k = 0; k < 8; ++k) pn = fmaf(__shfl(p, i * 8 + k, 64), m[k], pn);
                if ((r & 1) == 0 || r == GSZ - 1) pn = exp_renorm(pn, __shfl(pn, 0, 64));
                p = pn;
#pragma unroll
                for (int k = 0; k < 8; ++k) m[k] = mn[k];
            }
            astore(&ws[OFF_G2 + b * 64 + j * 8 + i], p);
            VMFENCE();
            if (tid == 0) astoreu(&flg[FLG_F2 + b], MAGIC);
        }

        // ---- wait for all 16 F2 (transitively covers all F1 payloads) ----
        for (;;) {
            bool ok = true;
            if (tid < NGRP)
                ok = aloadu(&flg[FLG_F2 + tid]) == MAGIC;
            if (__all(ok)) break;
            __builtin_amdgcn_s_sleep(1);
        }
        // ---- stage G2 (all 16) + own group's P into LDS ----
        for (int q = tid; q < NGRP * 64; q += 64) sG2[q] = aload(&ws[OFF_G2 + q]);
        for (int q = tid; q < GSZ * 64; q += 64)
            sGP[q] = aload(&ws[OFF_P + (size_t)g * GSZ * 64 + q]);

        if (tid < 16) {
            const int grp = tid >> 3, l8 = tid & 7;
            const int st = grp ? 8 : 1;
            const int boff = grp ? l8 : l8 * 8;
            // ---- redundant global dual scan over 16 group products ----
            float v[8], vb[8];
            {
                float a = Pi[obs[0] * NBLK + l8];
                float s0 = a;
                s0 += __shfl_xor(s0, 1); s0 += __shfl_xor(s0, 2); s0 += __shfl_xor(s0, 4);
                float rs0 = 1.0f / s0;
#pragma unroll
                for (int q = 0; q < 8; ++q) v[q] = grp ? 0.125f : __shfl(a, q, 8) * rs0;
                ll0 = __logf(s0);
            }
            const int cap = grp ? (NGRP - 1 - g) : g;
            if (cap == 0) {
#pragma unroll
                for (int q = 0; q < 8; ++q) vb[q] = v[q];
            }
            for (int r = 0; r < NGRP - 1; ++r) {
                int gi = grp ? (NGRP - 1 - r) : r;
                const float* mb = &sG2[gi * 64 + boff];
                float m[8];
#pragma unroll
                for (int q = 0; q < 8; ++q) m[q] = mb[q * st];
                float u = 0.f;
#pragma unroll
                for (int q = 0; q < 8; ++q) u = fmaf(v[q], m[q], u);
                float s = 0.f;
#pragma unroll
                for (int q = 0; q < 8; ++q) { float x = __shfl(u, q, 8); v[q] = x; s += x; }
                float rs = 1.0f / s;
#pragma unroll
                for (int q = 0; q < 8; ++q) v[q] *= rs;
                if (r + 1 == cap) {
#pragma unroll
                    for (int q = 0; q < 8; ++q) vb[q] = v[q];
                }
            }
            // ---- predicated advance to own chunk boundary (<=15 steps) ----
#pragma unroll
            for (int q = 0; q < 8; ++q) v[q] = vb[q];
            const int cnt = grp ? (GSZ - 1 - rIn) : rIn;
            for (int q = 0; q < GSZ - 1; ++q) {
                bool act = q < cnt;
                int qc = act ? q : 0;
                int lc = grp ? (GSZ - 1 - qc) : qc;
                const float* mb = &sGP[lc * 64 + boff];
                float m[8];
#pragma unroll
                for (int k = 0; k < 8; ++k) m[k] = mb[k * st];
                float u = 0.f;
#pragma unroll
                for (int k = 0; k < 8; ++k) u = fmaf(v[k], m[k], u);
                float s = 0.f;
                float vn[8];
#pragma unroll
                for (int k = 0; k < 8; ++k) { float x = __shfl(u, k, 8); vn[k] = x; s += x; }
                float rs = 1.0f / s;
#pragma unroll
                for (int k = 0; k < 8; ++k) v[k] = act ? vn[k] * rs : v[k];
            }
            // ---- within-chunk dual rescan from sM ----
            float* hist = grp ? sB : sA;
            hist[(grp ? n : 0) * 8 + l8] = v[l8];
            int mt0 = grp ? (n - 1) : 0;
            float m[8], mn[8];
#pragma unroll
            for (int q = 0; q < 8; ++q) m[q] = sM[mt0 * 64 + boff + q * st];
            float ll = 0.f;
            for (int rr = 0; rr < n; ++rr) {
                int rn2 = min(rr + 1, n - 1);
                int mtn = grp ? (n - 1 - rn2) : rn2;
#pragma unroll
                for (int q = 0; q < 8; ++q) mn[q] = sM[mtn * 64 + boff + q * st];
                float u = 0.f;
#pragma unroll
                for (int q = 0; q < 8; ++q) u = fmaf(v[q], m[q], u);
                float s = 0.f;
#pragma unroll
                for (int q = 0; q < 8; ++q) { float x = __shfl(u, q, 8); v[q] = x; s += x; }
                float rs = 1.0f / s;
#pragma unroll
                for (int q = 0; q < 8; ++q) v[q] *= rs;
                hist[(grp ? (n - 1 - rr) : (rr + 1)) * 8 + l8] = v[l8];
                ll += __logf(s);
#pragma unroll
                for (int q = 0; q < 8; ++q) m[q] = mn[q];
            }
            if (tid == 0) astore(&ws[OFF_LLP + b], ll);
        }
        VMFENCE();
        if (tid == 0) astoreu(&flg[FLG_F3 + b], MAGIC);
    }
    __syncthreads();   // join fill + scan; own rows are zeroed, sA/sB ready

    // ---- scatter gamma windows into own pre-zeroed rows (256 threads) -----
    {
        const int rr = tid >> 3, ii = tid & 7;
        float gp = sA[rr * 8 + ii] * sB[rr * 8 + ii];
        float gs = gp;
        gs += __shfl_xor(gs, 1); gs += __shfl_xor(gs, 2); gs += __shfl_xor(gs, 4);
        out[1 + (size_t)(t0 + rr) * NSTATES + sObs[rr] * NBLK + ii] = gp / gs;
    }

    // ---- block 0, wave 0: deterministic log-lik reduction -> out[0] -------
    if (b == 0 && tid < 64) {
        for (;;) {
            bool ok = true;
#pragma unroll
            for (int q = 0; q < 4; ++q)
                ok = ok && (aloadu(&flg[FLG_F3 + tid * 4 + q]) == MAGIC);
            if (__all(ok)) break;
            __builtin_amdgcn_s_sleep(1);
        }
        float part = 0.f;
#pragma unroll
        for (int q = 0; q < 4; ++q) part += aload(&ws[OFF_LLP + tid * 4 + q]);
        part += __shfl_xor(part, 32); part += __shfl_xor(part, 16);
        part += __shfl_xor(part, 8);  part += __shfl_xor(part, 4);
        part += __shfl_xor(part, 2);  part += __shfl_xor(part, 1);
        if (tid == 0) out[0] = part + ll0;
    }
}

extern "C" void kernel_launch(void* const* d_in, const int* in_sizes, int n_in,
                              void* d_out, int out_size, void* d_ws, size_t ws_size,
                              hipStream_t stream)
{
    const float* T   = (const float*)d_in[0];
    const float* Pi  = (const float*)d_in[1];
    const int*   obs = (const int*)d_in[2];
    float* out = (float*)d_out;
    float* ws  = (float*)d_ws;

    void* args[] = {(void*)&T, (void*)&Pi, (void*)&obs, (void*)&out, (void*)&ws};
    hipLaunchCooperativeKernel((const void*)kFB, dim3(NCH), dim3(256), args, 0, stream);
}